// Round 9
// baseline (454.338 us; speedup 1.0000x reference)
//
#include <hip/hip_runtime.h>
#include <hip/hip_bf16.h>

#define N_NODES 100000
#define M_PAD   100096   // 391 * 256: GEMM blocks (2 m-tiles of 128) never read OOB
#define N_EDGES 400000
#define IN_DIM  69
#define KPX     96       // Xs pitch (gather space for layer-1 aggregate)
#define KPA     128      // Xa pitch (layer-1 GEMM K, padded to BK multiple)
#define HID     256
#define NG      4096
#define SCAN_B  391      // ceil(N_NODES / 256)
#define FILL_B  1563     // ceil(N_EDGES / 256)

typedef __attribute__((ext_vector_type(8))) short bf16x8;
typedef __attribute__((ext_vector_type(4))) float f32x4;
typedef unsigned short u16;
typedef unsigned int   u32;

__device__ __forceinline__ float b2f(u16 v) {
    u32 x = ((u32)v) << 16;
    return __builtin_bit_cast(float, x);
}
__device__ __forceinline__ u16 f2b(float f) {
    u32 x = __builtin_bit_cast(u32, f);
    u32 r = (x + 0x7FFF + ((x >> 16) & 1)) >> 16;   // RNE
    return (u16)r;
}
__device__ __forceinline__ float lo16(u32 v) { return b2f((u16)(v & 0xffff)); }
__device__ __forceinline__ float hi16(u32 v) { return b2f((u16)(v >> 16)); }

__device__ __forceinline__ void acc8(float* a, uint4 w, float m) {
    a[0] = fmaf(m, lo16(w.x), a[0]); a[1] = fmaf(m, hi16(w.x), a[1]);
    a[2] = fmaf(m, lo16(w.y), a[2]); a[3] = fmaf(m, hi16(w.y), a[3]);
    a[4] = fmaf(m, lo16(w.z), a[4]); a[5] = fmaf(m, hi16(w.z), a[5]);
    a[6] = fmaf(m, lo16(w.w), a[6]); a[7] = fmaf(m, hi16(w.w), a[7]);
}
__device__ __forceinline__ void acc4(float* a, uint2 w, float m) {
    a[0] = fmaf(m, lo16(w.x), a[0]); a[1] = fmaf(m, hi16(w.x), a[1]);
    a[2] = fmaf(m, lo16(w.y), a[2]); a[3] = fmaf(m, hi16(w.y), a[3]);
}

// async global->LDS, 16B per lane; LDS dest = wave-uniform base + lane*16
__device__ __forceinline__ void gl_lds16(const u16* g, u16* l) {
    __builtin_amdgcn_global_load_lds(
        (const __attribute__((address_space(1))) void*)g,
        (__attribute__((address_space(3))) void*)l, 16, 0, 0);
}

// ---- in-degree count (int) ----
__global__ void k_deg(const int* __restrict__ dst, int* __restrict__ deg) {
    int e = blockIdx.x * blockDim.x + threadIdx.x;
    if (e < N_EDGES) atomicAdd(&deg[dst[e]], 1);
}

// ---- local scan + dinv fused ----
__global__ void k_scan_local(const int* __restrict__ deg, int* __restrict__ rowptr,
                             int* __restrict__ bsum, float* __restrict__ dinv) {
    __shared__ int s[256];
    int tid = threadIdx.x;
    int i = blockIdx.x * 256 + tid;
    int v = (i < N_NODES) ? deg[i] : 0;
    if (i < N_NODES) dinv[i] = rsqrtf((float)v + 1.0f);
    s[tid] = v;
    __syncthreads();
    #pragma unroll
    for (int off = 1; off < 256; off <<= 1) {
        int t = 0;
        if (tid >= off) t = s[tid - off];
        __syncthreads();
        if (tid >= off) s[tid] += t;
        __syncthreads();
    }
    if (i < N_NODES) rowptr[i] = s[tid] - v;          // exclusive
    if (tid == 255) bsum[blockIdx.x] = s[255];        // block total
}

__global__ void k_scan_bsum(int* __restrict__ bsum, int* __restrict__ boff) {
    __shared__ int s[512];
    int tid = threadIdx.x;
    int v = (tid < SCAN_B) ? bsum[tid] : 0;
    s[tid] = v;
    __syncthreads();
    #pragma unroll
    for (int off = 1; off < 512; off <<= 1) {
        int t = 0;
        if (tid >= off) t = s[tid - off];
        __syncthreads();
        if (tid >= off) s[tid] += t;
        __syncthreads();
    }
    if (tid < SCAN_B) boff[tid] = s[tid] - v;         // exclusive
}

__global__ void k_scan_add(int* __restrict__ rowptr, const int* __restrict__ boff) {
    int i = blockIdx.x * 256 + threadIdx.x;
    if (i < N_NODES) rowptr[i] += boff[blockIdx.x];
    if (i == 0) rowptr[N_NODES] = N_EDGES;
}

// ---- CSR fill + Xs = dinv.*x pad/scale, merged ----
__global__ __launch_bounds__(256) void k_fill_pad(const int* __restrict__ src,
                       const int* __restrict__ dst,
                       const int* __restrict__ rowptr, int* __restrict__ fill,
                       int* __restrict__ col,
                       const float* __restrict__ x, const float* __restrict__ dinv,
                       u16* __restrict__ xs) {
    if (blockIdx.x < FILL_B) {
        int e = blockIdx.x * 256 + threadIdx.x;
        if (e < N_EDGES) {
            int d = dst[e];
            int pos = rowptr[d] + atomicAdd(&fill[d], 1);
            col[pos] = src[e];
        }
    } else {
        int node = (blockIdx.x - FILL_B) * 4 + (threadIdx.x >> 6);
        if (node >= N_NODES) return;
        int lane = threadIdx.x & 63;
        if (lane >= 48) return;
        int d0 = lane * 2, d1 = lane * 2 + 1;
        float dv = dinv[node];
        const float* xr = x + (size_t)node * IN_DIM;
        float v0 = (d0 < IN_DIM) ? xr[d0] * dv : 0.0f;
        float v1 = (d1 < IN_DIM) ? xr[d1] * dv : 0.0f;
        u32 o = (u32)f2b(v0) | ((u32)f2b(v1) << 16);
        *(u32*)(xs + (size_t)node * KPX + d0) = o;
    }
}

// ---- merged prep: W1/W2/W3 transpose->bf16, W4@Wl fold, gptr search ----
__global__ void k_prep(const float* __restrict__ W1, const float* __restrict__ W2,
                       const float* __restrict__ W3, const float* __restrict__ W4,
                       const float* __restrict__ Wl, const float* __restrict__ b4,
                       const float* __restrict__ bl, const int* __restrict__ batch,
                       u16* __restrict__ Wt1, u16* __restrict__ Wt2, u16* __restrict__ Wt3,
                       float* __restrict__ W4l, float* __restrict__ c4, int* __restrict__ gptr) {
    int b = blockIdx.x;
    int t = threadIdx.x;
    if (b < KPA) {                       // Wt1 [256 x 128], zero-padded K
        Wt1[(size_t)t * KPA + b] = (b < IN_DIM) ? f2b(W1[(size_t)b * HID + t]) : (u16)0;
    } else if (b < KPA + HID) {          // Wt2 [256 x 256]
        int k = b - KPA;
        Wt2[(size_t)t * HID + k] = f2b(W2[(size_t)k * HID + t]);
    } else if (b < KPA + 2 * HID) {      // Wt3
        int k = b - KPA - HID;
        Wt3[(size_t)t * HID + k] = f2b(W3[(size_t)k * HID + t]);
    } else if (b == KPA + 2 * HID) {     // W4l = W4 @ Wl ; c4 = b4 @ Wl + bl
        float s0 = 0.0f, s1 = 0.0f;
        const float* wr = W4 + (size_t)t * HID;
        for (int j = 0; j < HID; ++j) {
            float w = wr[j];
            s0 += w * Wl[j * 2 + 0];
            s1 += w * Wl[j * 2 + 1];
        }
        W4l[t * 2 + 0] = s0;
        W4l[t * 2 + 1] = s1;
        if (t < 2) {
            float s = bl[t];
            for (int j = 0; j < HID; ++j) s += b4[j] * Wl[j * 2 + t];
            c4[t] = s;
        }
    } else {                             // gptr: lower_bound(batch, g)
        int g = (b - (KPA + 2 * HID + 1)) * 256 + t;
        if (g > NG) return;
        if (g == NG) { gptr[NG] = N_NODES; return; }
        int lo = 0, hi = N_NODES;
        while (lo < hi) {
            int mid = (lo + hi) >> 1;
            if (batch[mid] < g) lo = mid + 1; else hi = mid;
        }
        gptr[g] = lo;
    }
}

// ---- 96-dim aggregate -> Xa [M_PAD x 128]; 32 lanes/node, predicated unroll-8 ----
__global__ __launch_bounds__(256) void k_agg96(const int* __restrict__ rowptr,
                                               const int* __restrict__ col,
                                               const u16* __restrict__ xs,
                                               const float* __restrict__ dinv,
                                               u16* __restrict__ xa) {
    int node = blockIdx.x * 8 + (threadIdx.x >> 5);
    if (node >= N_NODES) return;
    int l = threadIdx.x & 31;
    int j = l * 4;
    if (l >= 24) {                       // K-pad region (dims 96..127) -> zero
        *(uint2*)(xa + (size_t)node * KPA + j) = make_uint2(0, 0);
        return;
    }
    const u16* xj = xs + j;
    float a[4];
    {
        uint2 v = *(const uint2*)(xj + (size_t)node * KPX);
        a[0] = lo16(v.x); a[1] = hi16(v.x); a[2] = lo16(v.y); a[3] = hi16(v.y);
    }
    int e = rowptr[node], end = rowptr[node + 1];
    for (; e < end; e += 8) {
        int idx[8]; float mm[8];
        #pragma unroll
        for (int u = 0; u < 8; ++u) {
            int ee = e + u;
            idx[u] = (ee < end) ? ee : e;
            mm[u]  = (ee < end) ? 1.0f : 0.0f;
        }
        mm[0] = 1.0f;
        uint2 w[8];
        #pragma unroll
        for (int u = 0; u < 8; ++u) w[u] = *(const uint2*)(xj + (size_t)col[idx[u]] * KPX);
        #pragma unroll
        for (int u = 0; u < 8; ++u) acc4(a, w[u], mm[u]);
    }
    float dv = dinv[node];
    uint2 o;
    o.x = (u32)f2b(a[0] * dv) | ((u32)f2b(a[1] * dv) << 16);
    o.y = (u32)f2b(a[2] * dv) | ((u32)f2b(a[3] * dv) << 16);
    *(uint2*)(xa + (size_t)node * KPA + j) = o;
}

// ---- 2-M-tile MFMA GEMM: block = 256 rows x 128 cols; B staged once per k-chunk ----
// grid (M_PAD/256, HID/128). MODE 0: Out = dinv[m]*(A@Wt^T). MODE 1: relu(A@Wt^T + bias).
template<int MODE>
__global__ __launch_bounds__(256) void k_gemm(const u16* __restrict__ A, int KP,
                                              const u16* __restrict__ Wt,
                                              const float* __restrict__ dinv,
                                              const float* __restrict__ bias,
                                              u16* __restrict__ Out) {
    // S = As0[128x64] | As1[128x64] | Bs[128x64], XOR-swizzled chunks, 48KB total
    __shared__ __align__(16) u16 S[3 * 128 * 64];

    const int tid  = threadIdx.x;
    const int wave = tid >> 6;
    const int lane = tid & 63;
    const int quad = lane >> 4;
    const int lm   = lane & 15;
    const int wr   = wave >> 1;          // wave m-half (0,1) within a 128-tile
    const int wc   = wave & 1;           // wave n-half (0,1)
    const int m0   = blockIdx.x * 256;
    const int n0   = blockIdx.y * 128;

    f32x4 acc[2][4][4] = {};

    const int sr = lane >> 3;
    const int sc = lane & 7;
    const int gc = sc ^ (sr & 7);

    for (int kt = 0; kt < KP; kt += 64) {
        __syncthreads();
        #pragma unroll
        for (int i = 0; i < 4; ++i) {
            int s = wave * 4 + i;                    // segment 0..15 (8 rows each)
            int r = s * 8 + sr;
            gl_lds16(A  + (size_t)(m0 + r) * KP + kt + gc * 8,       S + s * 512);
            gl_lds16(A  + (size_t)(m0 + 128 + r) * KP + kt + gc * 8, S + 8192 + s * 512);
            gl_lds16(Wt + (size_t)(n0 + r) * KP + kt + gc * 8,       S + 16384 + s * 512);
        }
        __syncthreads();

        #pragma unroll
        for (int st = 0; st < 2; ++st) {
            bf16x8 a0[4], a1[4], bb[4];
            const int slot = ((st * 4 + quad) ^ (lm & 7)) * 8;
            #pragma unroll
            for (int rt = 0; rt < 4; ++rt) {
                a0[rt] = *(const bf16x8*)(S + (wr * 64 + rt * 16 + lm) * 64 + slot);
                a1[rt] = *(const bf16x8*)(S + 8192 + (wr * 64 + rt * 16 + lm) * 64 + slot);
            }
            #pragma unroll
            for (int ct = 0; ct < 4; ++ct)
                bb[ct] = *(const bf16x8*)(S + 16384 + (wc * 64 + ct * 16 + lm) * 64 + slot);
            #pragma unroll
            for (int rt = 0; rt < 4; ++rt)
                #pragma unroll
                for (int ct = 0; ct < 4; ++ct) {
                    acc[0][rt][ct] = __builtin_amdgcn_mfma_f32_16x16x32_bf16(a0[rt], bb[ct], acc[0][rt][ct], 0, 0, 0);
                    acc[1][rt][ct] = __builtin_amdgcn_mfma_f32_16x16x32_bf16(a1[rt], bb[ct], acc[1][rt][ct], 0, 0, 0);
                }
        }
    }

    #pragma unroll
    for (int mt = 0; mt < 2; ++mt) {
        #pragma unroll
        for (int rt = 0; rt < 4; ++rt) {
            #pragma unroll
            for (int reg = 0; reg < 4; ++reg) {
                int m = m0 + mt * 128 + wr * 64 + rt * 16 + quad * 4 + reg;
                if (m >= N_NODES) continue;
                float dv = (MODE == 0) ? dinv[m] : 0.0f;
                #pragma unroll
                for (int ct = 0; ct < 4; ++ct) {
                    int n = n0 + wc * 64 + ct * 16 + lm;
                    float v = acc[mt][rt][ct][reg];
                    if (MODE == 0) v *= dv;
                    else           v = fmaxf(v + bias[n], 0.0f);
                    Out[(size_t)m * HID + n] = f2b(v);
                }
            }
        }
    }
}

// ---- 256-dim aggregate + bias + relu; 32 lanes/node, 16B loads, predicated unroll-8 ----
__global__ __launch_bounds__(256) void k_agg256(const int* __restrict__ rowptr,
                                                const int* __restrict__ col,
                                                const u16* __restrict__ g,
                                                const float* __restrict__ dinv,
                                                const float* __restrict__ bias,
                                                u16* __restrict__ Xout) {
    int node = blockIdx.x * 8 + (threadIdx.x >> 5);
    if (node >= N_NODES) return;
    int l = threadIdx.x & 31;
    int j = l * 8;
    const u16* gj = g + j;

    float a[8];
    {
        uint4 v = *(const uint4*)(gj + (size_t)node * HID);
        a[0] = lo16(v.x); a[1] = hi16(v.x); a[2] = lo16(v.y); a[3] = hi16(v.y);
        a[4] = lo16(v.z); a[5] = hi16(v.z); a[6] = lo16(v.w); a[7] = hi16(v.w);
    }
    int e = rowptr[node], end = rowptr[node + 1];
    for (; e < end; e += 8) {
        int idx[8]; float mm[8];
        #pragma unroll
        for (int u = 0; u < 8; ++u) {
            int ee = e + u;
            idx[u] = (ee < end) ? ee : e;
            mm[u]  = (ee < end) ? 1.0f : 0.0f;
        }
        mm[0] = 1.0f;
        uint4 w[8];
        #pragma unroll
        for (int u = 0; u < 8; ++u) w[u] = *(const uint4*)(gj + (size_t)col[idx[u]] * HID);
        #pragma unroll
        for (int u = 0; u < 8; ++u) acc8(a, w[u], mm[u]);
    }
    float dv = dinv[node];
    float4 b0 = *(const float4*)(bias + j);
    float4 b1 = *(const float4*)(bias + j + 4);
    float r0 = fmaxf(fmaf(a[0], dv, b0.x), 0.0f);
    float r1 = fmaxf(fmaf(a[1], dv, b0.y), 0.0f);
    float r2 = fmaxf(fmaf(a[2], dv, b0.z), 0.0f);
    float r3 = fmaxf(fmaf(a[3], dv, b0.w), 0.0f);
    float r4 = fmaxf(fmaf(a[4], dv, b1.x), 0.0f);
    float r5 = fmaxf(fmaf(a[5], dv, b1.y), 0.0f);
    float r6 = fmaxf(fmaf(a[6], dv, b1.z), 0.0f);
    float r7 = fmaxf(fmaf(a[7], dv, b1.w), 0.0f);
    uint4 o;
    o.x = (u32)f2b(r0) | ((u32)f2b(r1) << 16);
    o.y = (u32)f2b(r2) | ((u32)f2b(r3) << 16);
    o.z = (u32)f2b(r4) | ((u32)f2b(r5) << 16);
    o.w = (u32)f2b(r6) | ((u32)f2b(r7) << 16);
    *(uint4*)(Xout + (size_t)node * HID + j) = o;
}

// ---- fused layer-3 agg + relu + W4l projection -> g4 [N x 2] f32 ----
__global__ __launch_bounds__(256) void k_agg_head(const int* __restrict__ rowptr,
                                                  const int* __restrict__ col,
                                                  const u16* __restrict__ g,
                                                  const float* __restrict__ dinv,
                                                  const float* __restrict__ bias,
                                                  const float* __restrict__ W4l,
                                                  float* __restrict__ g4) {
    __shared__ float2 sW[HID];
    sW[threadIdx.x] = *(const float2*)(W4l + threadIdx.x * 2);
    __syncthreads();

    int node = blockIdx.x * 8 + (threadIdx.x >> 5);
    if (node >= N_NODES) return;
    int l = threadIdx.x & 31;
    int j = l * 8;
    const u16* gj = g + j;

    float a[8];
    {
        uint4 v = *(const uint4*)(gj + (size_t)node * HID);
        a[0] = lo16(v.x); a[1] = hi16(v.x); a[2] = lo16(v.y); a[3] = hi16(v.y);
        a[4] = lo16(v.z); a[5] = hi16(v.z); a[6] = lo16(v.w); a[7] = hi16(v.w);
    }
    int e = rowptr[node], end = rowptr[node + 1];
    for (; e < end; e += 8) {
        int idx[8]; float mm[8];
        #pragma unroll
        for (int u = 0; u < 8; ++u) {
            int ee = e + u;
            idx[u] = (ee < end) ? ee : e;
            mm[u]  = (ee < end) ? 1.0f : 0.0f;
        }
        mm[0] = 1.0f;
        uint4 w[8];
        #pragma unroll
        for (int u = 0; u < 8; ++u) w[u] = *(const uint4*)(gj + (size_t)col[idx[u]] * HID);
        #pragma unroll
        for (int u = 0; u < 8; ++u) acc8(a, w[u], mm[u]);
    }
    float dv = dinv[node];
    float4 b0 = *(const float4*)(bias + j);
    float4 b1 = *(const float4*)(bias + j + 4);
    float r[8];
    r[0] = fmaxf(fmaf(a[0], dv, b0.x), 0.0f);
    r[1] = fmaxf(fmaf(a[1], dv, b0.y), 0.0f);
    r[2] = fmaxf(fmaf(a[2], dv, b0.z), 0.0f);
    r[3] = fmaxf(fmaf(a[3], dv, b0.w), 0.0f);
    r[4] = fmaxf(fmaf(a[4], dv, b1.x), 0.0f);
    r[5] = fmaxf(fmaf(a[5], dv, b1.y), 0.0f);
    r[6] = fmaxf(fmaf(a[6], dv, b1.z), 0.0f);
    r[7] = fmaxf(fmaf(a[7], dv, b1.w), 0.0f);
    float s0 = 0.0f, s1 = 0.0f;
    #pragma unroll
    for (int i = 0; i < 8; ++i) {
        float2 w = sW[j + i];
        s0 = fmaf(r[i], w.x, s0);
        s1 = fmaf(r[i], w.y, s1);
    }
    #pragma unroll
    for (int off = 16; off >= 1; off >>= 1) {
        s0 += __shfl_down(s0, off, 32);
        s1 += __shfl_down(s1, off, 32);
    }
    if (l == 0)
        *(float2*)(g4 + (size_t)node * 2) = make_float2(s0 * dv, s1 * dv);
}

// ---- fused tail: per-graph, aggregate g4 over edges + mean-pool + c4 -> out ----
// one wave per graph; lane owns whole nodes (g4/col tables are small & L2-hot).
__global__ __launch_bounds__(256) void k_tail(const int* __restrict__ rowptr,
                                              const int* __restrict__ col,
                                              const float* __restrict__ g4,
                                              const float* __restrict__ dinv,
                                              const int* __restrict__ gptr,
                                              const float* __restrict__ c4,
                                              float* __restrict__ out) {
    int gph = blockIdx.x * 4 + (threadIdx.x >> 6);
    if (gph >= NG) return;
    int lane = threadIdx.x & 63;
    int b = gptr[gph], e = gptr[gph + 1];
    float s0 = 0.0f, s1 = 0.0f;
    for (int n = b + lane; n < e; n += 64) {
        float2 a = *(const float2*)(g4 + (size_t)n * 2);
        int ee = rowptr[n], eend = rowptr[n + 1];
        for (; ee < eend; ++ee) {
            float2 w = *(const float2*)(g4 + (size_t)col[ee] * 2);
            a.x += w.x; a.y += w.y;
        }
        float dv = dinv[n];
        s0 = fmaf(a.x, dv, s0);
        s1 = fmaf(a.y, dv, s1);
    }
    #pragma unroll
    for (int off = 32; off >= 1; off >>= 1) {
        s0 += __shfl_down(s0, off);
        s1 += __shfl_down(s1, off);
    }
    if (lane == 0) {
        float inv = 1.0f / fmaxf((float)(e - b), 1.0f);
        out[gph * 2 + 0] = s0 * inv + c4[0];
        out[gph * 2 + 1] = s1 * inv + c4[1];
    }
}

extern "C" void kernel_launch(void* const* d_in, const int* in_sizes, int n_in,
                              void* d_out, int out_size, void* d_ws, size_t ws_size,
                              hipStream_t stream) {
    const float* x   = (const float*)d_in[0];
    const int* ei    = (const int*)d_in[1];
    const int* src   = ei;
    const int* dst   = ei + N_EDGES;
    const int* batch = (const int*)d_in[2];
    const float* W1 = (const float*)d_in[3];  const float* b1 = (const float*)d_in[4];
    const float* W2 = (const float*)d_in[5];  const float* b2 = (const float*)d_in[6];
    const float* W3 = (const float*)d_in[7];  const float* b3 = (const float*)d_in[8];
    const float* W4 = (const float*)d_in[9];  const float* b4 = (const float*)d_in[10];
    const float* Wl = (const float*)d_in[11]; const float* bl = (const float*)d_in[12];
    float* out = (float*)d_out;

    // ---- workspace layout ----
    char* p = (char*)d_ws;
    auto take = [&](size_t bytes) { char* r = p; p += (bytes + 255) & ~(size_t)255; return r; };
    size_t zbytes = (size_t)(N_NODES + N_NODES) * 4;   // deg | fill
    int*   deg  = (int*)take(zbytes);
    int*   fill = deg + N_NODES;
    float* dinv = (float*)take((size_t)N_NODES * sizeof(float));
    int* rowptr = (int*)take((size_t)(N_NODES + 1) * sizeof(int));
    int* col    = (int*)take((size_t)N_EDGES * sizeof(int));
    int* bsum   = (int*)take((size_t)SCAN_B * sizeof(int));
    int* boff   = (int*)take((size_t)SCAN_B * sizeof(int));
    int* gptr   = (int*)take((size_t)(NG + 1) * sizeof(int));
    float* W4l  = (float*)take((size_t)HID * 2 * sizeof(float));
    float* c4   = (float*)take(2 * sizeof(float));
    float* g4   = (float*)take((size_t)N_NODES * 2 * sizeof(float));
    u16* Wt1 = (u16*)take((size_t)HID * KPA * 2);
    u16* Wt2 = (u16*)take((size_t)HID * HID * 2);
    u16* Wt3 = (u16*)take((size_t)HID * HID * 2);
    u16* Xs  = (u16*)take((size_t)N_NODES * KPX * 2);
    u16* Xa  = (u16*)take((size_t)M_PAD * KPA * 2);    // padded rows for GEMM staging
    u16* Gbuf = (u16*)take((size_t)N_NODES * HID * 2);
    u16* Xbuf = (u16*)take((size_t)M_PAD * HID * 2);   // padded rows for GEMM staging

    hipMemsetAsync(deg, 0, zbytes, stream);

    // CSR build + norms + prep
    k_deg<<<(N_EDGES + 255) / 256, 256, 0, stream>>>(dst, deg);
    k_scan_local<<<SCAN_B, 256, 0, stream>>>(deg, rowptr, bsum, dinv);
    k_scan_bsum<<<1, 512, 0, stream>>>(bsum, boff);
    k_scan_add<<<SCAN_B, 256, 0, stream>>>(rowptr, boff);
    k_fill_pad<<<FILL_B + (N_NODES + 3) / 4, 256, 0, stream>>>(src, dst, rowptr, fill, col,
                                                               x, dinv, Xs);
    k_prep<<<KPA + 2 * HID + 1 + (NG + 256) / 256, 256, 0, stream>>>(
        W1, W2, W3, W4, Wl, b4, bl, batch, Wt1, Wt2, Wt3, W4l, c4, gptr);

    const int nb8 = (N_NODES + 7) / 8;
    const dim3 gemm_grid(M_PAD / 256, HID / 128);

    // layer 1: aggregate-first in input space, bias+relu fused in GEMM
    k_agg96<<<nb8, 256, 0, stream>>>(rowptr, col, Xs, dinv, Xa);
    k_gemm<1><<<gemm_grid, 256, 0, stream>>>(Xa, KPA, Wt1, dinv, b1, Xbuf);
    // layer 2
    k_gemm<0><<<gemm_grid, 256, 0, stream>>>(Xbuf, HID, Wt2, dinv, b2, Gbuf);
    k_agg256<<<nb8, 256, 0, stream>>>(rowptr, col, Gbuf, dinv, b2, Xbuf);
    // layer 3 GEMM -> g3; then fused agg+relu+head projection -> g4
    k_gemm<0><<<gemm_grid, 256, 0, stream>>>(Xbuf, HID, Wt3, dinv, b3, Gbuf);
    k_agg_head<<<nb8, 256, 0, stream>>>(rowptr, col, Gbuf, dinv, b3, W4l, g4);
    // fused tail: 2-dim aggregate + mean-pool + head constant
    k_tail<<<(NG + 3) / 4, 256, 0, stream>>>(rowptr, col, g4, dinv, gptr, c4, out);
}

// Round 10
// 373.407 us; speedup vs baseline: 1.2167x; 1.2167x over previous
//
#include <hip/hip_runtime.h>
#include <hip/hip_bf16.h>

#define N_NODES 100000
#define M_PAD   100096   // 782 * 128, so 128-row GEMM tiles never read OOB
#define N_EDGES 400000
#define IN_DIM  69
#define KPX     96       // Xs pitch (gather space for layer-1 aggregate)
#define KPA     128      // Xa pitch (layer-1 GEMM K, padded to BK multiple)
#define HID     256
#define NG      4096
#define SCAN_B  391      // ceil(N_NODES / 256)
#define FILL_B  1563     // ceil(N_EDGES / 256)

typedef __attribute__((ext_vector_type(8))) short bf16x8;
typedef __attribute__((ext_vector_type(4))) float f32x4;
typedef unsigned short u16;
typedef unsigned int   u32;

__device__ __forceinline__ float b2f(u16 v) {
    u32 x = ((u32)v) << 16;
    return __builtin_bit_cast(float, x);
}
__device__ __forceinline__ u16 f2b(float f) {
    u32 x = __builtin_bit_cast(u32, f);
    u32 r = (x + 0x7FFF + ((x >> 16) & 1)) >> 16;   // RNE
    return (u16)r;
}
__device__ __forceinline__ float lo16(u32 v) { return b2f((u16)(v & 0xffff)); }
__device__ __forceinline__ float hi16(u32 v) { return b2f((u16)(v >> 16)); }

__device__ __forceinline__ void acc8(float* a, uint4 w, float m) {
    a[0] = fmaf(m, lo16(w.x), a[0]); a[1] = fmaf(m, hi16(w.x), a[1]);
    a[2] = fmaf(m, lo16(w.y), a[2]); a[3] = fmaf(m, hi16(w.y), a[3]);
    a[4] = fmaf(m, lo16(w.z), a[4]); a[5] = fmaf(m, hi16(w.z), a[5]);
    a[6] = fmaf(m, lo16(w.w), a[6]); a[7] = fmaf(m, hi16(w.w), a[7]);
}
__device__ __forceinline__ void acc4(float* a, uint2 w, float m) {
    a[0] = fmaf(m, lo16(w.x), a[0]); a[1] = fmaf(m, hi16(w.x), a[1]);
    a[2] = fmaf(m, lo16(w.y), a[2]); a[3] = fmaf(m, hi16(w.y), a[3]);
}

// async global->LDS, 16B per lane; LDS dest = wave-uniform base + lane*16
__device__ __forceinline__ void gl_lds16(const u16* g, u16* l) {
    __builtin_amdgcn_global_load_lds(
        (const __attribute__((address_space(1))) void*)g,
        (__attribute__((address_space(3))) void*)l, 16, 0, 0);
}

// ---- in-degree count (int) ----
__global__ void k_deg(const int* __restrict__ dst, int* __restrict__ deg) {
    int e = blockIdx.x * blockDim.x + threadIdx.x;
    if (e < N_EDGES) atomicAdd(&deg[dst[e]], 1);
}

// ---- local scan + dinv fused ----
__global__ void k_scan_local(const int* __restrict__ deg, int* __restrict__ rowptr,
                             int* __restrict__ bsum, float* __restrict__ dinv) {
    __shared__ int s[256];
    int tid = threadIdx.x;
    int i = blockIdx.x * 256 + tid;
    int v = (i < N_NODES) ? deg[i] : 0;
    if (i < N_NODES) dinv[i] = rsqrtf((float)v + 1.0f);
    s[tid] = v;
    __syncthreads();
    #pragma unroll
    for (int off = 1; off < 256; off <<= 1) {
        int t = 0;
        if (tid >= off) t = s[tid - off];
        __syncthreads();
        if (tid >= off) s[tid] += t;
        __syncthreads();
    }
    if (i < N_NODES) rowptr[i] = s[tid] - v;          // exclusive
    if (tid == 255) bsum[blockIdx.x] = s[255];        // block total
}

__global__ void k_scan_bsum(int* __restrict__ bsum, int* __restrict__ boff) {
    __shared__ int s[512];
    int tid = threadIdx.x;
    int v = (tid < SCAN_B) ? bsum[tid] : 0;
    s[tid] = v;
    __syncthreads();
    #pragma unroll
    for (int off = 1; off < 512; off <<= 1) {
        int t = 0;
        if (tid >= off) t = s[tid - off];
        __syncthreads();
        if (tid >= off) s[tid] += t;
        __syncthreads();
    }
    if (tid < SCAN_B) boff[tid] = s[tid] - v;         // exclusive
}

__global__ void k_scan_add(int* __restrict__ rowptr, const int* __restrict__ boff) {
    int i = blockIdx.x * 256 + threadIdx.x;
    if (i < N_NODES) rowptr[i] += boff[blockIdx.x];
    if (i == 0) rowptr[N_NODES] = N_EDGES;
}

// ---- CSR fill + Xs = dinv.*x pad/scale, merged ----
__global__ __launch_bounds__(256) void k_fill_pad(const int* __restrict__ src,
                       const int* __restrict__ dst,
                       const int* __restrict__ rowptr, int* __restrict__ fill,
                       int* __restrict__ col,
                       const float* __restrict__ x, const float* __restrict__ dinv,
                       u16* __restrict__ xs) {
    if (blockIdx.x < FILL_B) {
        int e = blockIdx.x * 256 + threadIdx.x;
        if (e < N_EDGES) {
            int d = dst[e];
            int pos = rowptr[d] + atomicAdd(&fill[d], 1);
            col[pos] = src[e];
        }
    } else {
        int node = (blockIdx.x - FILL_B) * 4 + (threadIdx.x >> 6);
        if (node >= N_NODES) return;
        int lane = threadIdx.x & 63;
        if (lane >= 48) return;
        int d0 = lane * 2, d1 = lane * 2 + 1;
        float dv = dinv[node];
        const float* xr = x + (size_t)node * IN_DIM;
        float v0 = (d0 < IN_DIM) ? xr[d0] * dv : 0.0f;
        float v1 = (d1 < IN_DIM) ? xr[d1] * dv : 0.0f;
        u32 o = (u32)f2b(v0) | ((u32)f2b(v1) << 16);
        *(u32*)(xs + (size_t)node * KPX + d0) = o;
    }
}

// ---- merged prep: W1/W2/W3 transpose->bf16, W4@Wl fold, gptr search ----
__global__ void k_prep(const float* __restrict__ W1, const float* __restrict__ W2,
                       const float* __restrict__ W3, const float* __restrict__ W4,
                       const float* __restrict__ Wl, const float* __restrict__ b4,
                       const float* __restrict__ bl, const int* __restrict__ batch,
                       u16* __restrict__ Wt1, u16* __restrict__ Wt2, u16* __restrict__ Wt3,
                       float* __restrict__ W4l, float* __restrict__ c4, int* __restrict__ gptr) {
    int b = blockIdx.x;
    int t = threadIdx.x;
    if (b < KPA) {                       // Wt1 [256 x 128], zero-padded K
        Wt1[(size_t)t * KPA + b] = (b < IN_DIM) ? f2b(W1[(size_t)b * HID + t]) : (u16)0;
    } else if (b < KPA + HID) {          // Wt2 [256 x 256]
        int k = b - KPA;
        Wt2[(size_t)t * HID + k] = f2b(W2[(size_t)k * HID + t]);
    } else if (b < KPA + 2 * HID) {      // Wt3
        int k = b - KPA - HID;
        Wt3[(size_t)t * HID + k] = f2b(W3[(size_t)k * HID + t]);
    } else if (b == KPA + 2 * HID) {     // W4l = W4 @ Wl ; c4 = b4 @ Wl + bl
        float s0 = 0.0f, s1 = 0.0f;
        const float* wr = W4 + (size_t)t * HID;
        for (int j = 0; j < HID; ++j) {
            float w = wr[j];
            s0 += w * Wl[j * 2 + 0];
            s1 += w * Wl[j * 2 + 1];
        }
        W4l[t * 2 + 0] = s0;
        W4l[t * 2 + 1] = s1;
        if (t < 2) {
            float s = bl[t];
            for (int j = 0; j < HID; ++j) s += b4[j] * Wl[j * 2 + t];
            c4[t] = s;
        }
    } else {                             // gptr: lower_bound(batch, g)
        int g = (b - (KPA + 2 * HID + 1)) * 256 + t;
        if (g > NG) return;
        if (g == NG) { gptr[NG] = N_NODES; return; }
        int lo = 0, hi = N_NODES;
        while (lo < hi) {
            int mid = (lo + hi) >> 1;
            if (batch[mid] < g) lo = mid + 1; else hi = mid;
        }
        gptr[g] = lo;
    }
}

// ---- 96-dim aggregate -> Xa [M_PAD x 128]; 32 lanes/node, predicated unroll-8 ----
__global__ __launch_bounds__(256) void k_agg96(const int* __restrict__ rowptr,
                                               const int* __restrict__ col,
                                               const u16* __restrict__ xs,
                                               const float* __restrict__ dinv,
                                               u16* __restrict__ xa) {
    int node = blockIdx.x * 8 + (threadIdx.x >> 5);
    if (node >= N_NODES) return;
    int l = threadIdx.x & 31;
    int j = l * 4;
    if (l >= 24) {                       // K-pad region (dims 96..127) -> zero
        *(uint2*)(xa + (size_t)node * KPA + j) = make_uint2(0, 0);
        return;
    }
    const u16* xj = xs + j;
    float a[4];
    {
        uint2 v = *(const uint2*)(xj + (size_t)node * KPX);
        a[0] = lo16(v.x); a[1] = hi16(v.x); a[2] = lo16(v.y); a[3] = hi16(v.y);
    }
    int e = rowptr[node], end = rowptr[node + 1];
    for (; e < end; e += 8) {
        int idx[8]; float mm[8];
        #pragma unroll
        for (int u = 0; u < 8; ++u) {
            int ee = e + u;
            idx[u] = (ee < end) ? ee : e;
            mm[u]  = (ee < end) ? 1.0f : 0.0f;
        }
        mm[0] = 1.0f;
        uint2 w[8];
        #pragma unroll
        for (int u = 0; u < 8; ++u) w[u] = *(const uint2*)(xj + (size_t)col[idx[u]] * KPX);
        #pragma unroll
        for (int u = 0; u < 8; ++u) acc4(a, w[u], mm[u]);
    }
    float dv = dinv[node];
    uint2 o;
    o.x = (u32)f2b(a[0] * dv) | ((u32)f2b(a[1] * dv) << 16);
    o.y = (u32)f2b(a[2] * dv) | ((u32)f2b(a[3] * dv) << 16);
    *(uint2*)(xa + (size_t)node * KPA + j) = o;
}

// ---- 128x128-tile MFMA GEMM, global_load_lds staging, XOR-swizzled LDS ----
// grid (HID/128, M_PAD/128): COLUMN index is blockIdx.x (fast-varying) so the
// two column-blocks of one row-band dispatch together -> 2nd gets A from L2.
// MODE 0: Out = dinv[m]*(A@Wt^T).  MODE 1: Out = relu(A@Wt^T + bias).
template<int MODE>
__global__ __launch_bounds__(256) void k_gemm(const u16* __restrict__ A, int KP,
                                              const u16* __restrict__ Wt,
                                              const float* __restrict__ dinv,
                                              const float* __restrict__ bias,
                                              u16* __restrict__ Out) {
    __shared__ __align__(16) u16 As[128 * 64];   // [row][chunk ^ (row&7)]
    __shared__ __align__(16) u16 Bs[128 * 64];

    const int tid  = threadIdx.x;
    const int wave = tid >> 6;
    const int lane = tid & 63;
    const int quad = lane >> 4;
    const int lm   = lane & 15;
    const int wr   = wave >> 1;
    const int wc   = wave & 1;
    const int m0   = blockIdx.y * 128;   // row band (slow axis)
    const int n0   = blockIdx.x * 128;   // column  (fast axis)

    f32x4 acc[4][4] = {};

    const int sr = lane >> 3;
    const int sc = lane & 7;
    const int gc = sc ^ (sr & 7);

    for (int kt = 0; kt < KP; kt += 64) {
        __syncthreads();
        #pragma unroll
        for (int i = 0; i < 4; ++i) {
            int s = wave * 4 + i;
            int r = s * 8 + sr;
            const u16* ga = A  + (size_t)(m0 + r) * KP + kt + gc * 8;
            const u16* gb = Wt + (size_t)(n0 + r) * KP + kt + gc * 8;
            gl_lds16(ga, As + s * 512);
            gl_lds16(gb, Bs + s * 512);
        }
        __syncthreads();

        #pragma unroll
        for (int st = 0; st < 2; ++st) {
            bf16x8 af[4], bfr[4];
            const int slot = ((st * 4 + quad) ^ (lm & 7)) * 8;
            #pragma unroll
            for (int rt = 0; rt < 4; ++rt)
                af[rt] = *(const bf16x8*)(As + (wr * 64 + rt * 16 + lm) * 64 + slot);
            #pragma unroll
            for (int ct = 0; ct < 4; ++ct)
                bfr[ct] = *(const bf16x8*)(Bs + (wc * 64 + ct * 16 + lm) * 64 + slot);
            #pragma unroll
            for (int rt = 0; rt < 4; ++rt)
                #pragma unroll
                for (int ct = 0; ct < 4; ++ct)
                    acc[rt][ct] = __builtin_amdgcn_mfma_f32_16x16x32_bf16(af[rt], bfr[ct], acc[rt][ct], 0, 0, 0);
        }
    }

    #pragma unroll
    for (int rt = 0; rt < 4; ++rt) {
        #pragma unroll
        for (int reg = 0; reg < 4; ++reg) {
            int m = m0 + wr * 64 + rt * 16 + quad * 4 + reg;
            if (m >= N_NODES) continue;
            float dv = (MODE == 0) ? dinv[m] : 0.0f;
            #pragma unroll
            for (int ct = 0; ct < 4; ++ct) {
                int n = n0 + wc * 64 + ct * 16 + lm;
                float v = acc[rt][ct][reg];
                if (MODE == 0) v *= dv;
                else           v = fmaxf(v + bias[n], 0.0f);
                Out[(size_t)m * HID + n] = f2b(v);
            }
        }
    }
}

// ---- 256-dim aggregate + bias + relu; 32 lanes/node, 16B loads, predicated unroll-8 ----
__global__ __launch_bounds__(256) void k_agg256(const int* __restrict__ rowptr,
                                                const int* __restrict__ col,
                                                const u16* __restrict__ g,
                                                const float* __restrict__ dinv,
                                                const float* __restrict__ bias,
                                                u16* __restrict__ Xout) {
    int node = blockIdx.x * 8 + (threadIdx.x >> 5);
    if (node >= N_NODES) return;
    int l = threadIdx.x & 31;
    int j = l * 8;
    const u16* gj = g + j;

    float a[8];
    {
        uint4 v = *(const uint4*)(gj + (size_t)node * HID);
        a[0] = lo16(v.x); a[1] = hi16(v.x); a[2] = lo16(v.y); a[3] = hi16(v.y);
        a[4] = lo16(v.z); a[5] = hi16(v.z); a[6] = lo16(v.w); a[7] = hi16(v.w);
    }
    int e = rowptr[node], end = rowptr[node + 1];
    for (; e < end; e += 8) {
        int idx[8]; float mm[8];
        #pragma unroll
        for (int u = 0; u < 8; ++u) {
            int ee = e + u;
            idx[u] = (ee < end) ? ee : e;
            mm[u]  = (ee < end) ? 1.0f : 0.0f;
        }
        mm[0] = 1.0f;
        uint4 w[8];
        #pragma unroll
        for (int u = 0; u < 8; ++u) w[u] = *(const uint4*)(gj + (size_t)col[idx[u]] * HID);
        #pragma unroll
        for (int u = 0; u < 8; ++u) acc8(a, w[u], mm[u]);
    }
    float dv = dinv[node];
    float4 b0 = *(const float4*)(bias + j);
    float4 b1 = *(const float4*)(bias + j + 4);
    float r0 = fmaxf(fmaf(a[0], dv, b0.x), 0.0f);
    float r1 = fmaxf(fmaf(a[1], dv, b0.y), 0.0f);
    float r2 = fmaxf(fmaf(a[2], dv, b0.z), 0.0f);
    float r3 = fmaxf(fmaf(a[3], dv, b0.w), 0.0f);
    float r4 = fmaxf(fmaf(a[4], dv, b1.x), 0.0f);
    float r5 = fmaxf(fmaf(a[5], dv, b1.y), 0.0f);
    float r6 = fmaxf(fmaf(a[6], dv, b1.z), 0.0f);
    float r7 = fmaxf(fmaf(a[7], dv, b1.w), 0.0f);
    uint4 o;
    o.x = (u32)f2b(r0) | ((u32)f2b(r1) << 16);
    o.y = (u32)f2b(r2) | ((u32)f2b(r3) << 16);
    o.z = (u32)f2b(r4) | ((u32)f2b(r5) << 16);
    o.w = (u32)f2b(r6) | ((u32)f2b(r7) << 16);
    *(uint4*)(Xout + (size_t)node * HID + j) = o;
}

// ---- fused layer-3 agg + relu + W4l projection -> g4 [N x 2] f32 ----
__global__ __launch_bounds__(256) void k_agg_head(const int* __restrict__ rowptr,
                                                  const int* __restrict__ col,
                                                  const u16* __restrict__ g,
                                                  const float* __restrict__ dinv,
                                                  const float* __restrict__ bias,
                                                  const float* __restrict__ W4l,
                                                  float* __restrict__ g4) {
    __shared__ float2 sW[HID];
    sW[threadIdx.x] = *(const float2*)(W4l + threadIdx.x * 2);
    __syncthreads();

    int node = blockIdx.x * 8 + (threadIdx.x >> 5);
    if (node >= N_NODES) return;
    int l = threadIdx.x & 31;
    int j = l * 8;
    const u16* gj = g + j;

    float a[8];
    {
        uint4 v = *(const uint4*)(gj + (size_t)node * HID);
        a[0] = lo16(v.x); a[1] = hi16(v.x); a[2] = lo16(v.y); a[3] = hi16(v.y);
        a[4] = lo16(v.z); a[5] = hi16(v.z); a[6] = lo16(v.w); a[7] = hi16(v.w);
    }
    int e = rowptr[node], end = rowptr[node + 1];
    for (; e < end; e += 8) {
        int idx[8]; float mm[8];
        #pragma unroll
        for (int u = 0; u < 8; ++u) {
            int ee = e + u;
            idx[u] = (ee < end) ? ee : e;
            mm[u]  = (ee < end) ? 1.0f : 0.0f;
        }
        mm[0] = 1.0f;
        uint4 w[8];
        #pragma unroll
        for (int u = 0; u < 8; ++u) w[u] = *(const uint4*)(gj + (size_t)col[idx[u]] * HID);
        #pragma unroll
        for (int u = 0; u < 8; ++u) acc8(a, w[u], mm[u]);
    }
    float dv = dinv[node];
    float4 b0 = *(const float4*)(bias + j);
    float4 b1 = *(const float4*)(bias + j + 4);
    float r[8];
    r[0] = fmaxf(fmaf(a[0], dv, b0.x), 0.0f);
    r[1] = fmaxf(fmaf(a[1], dv, b0.y), 0.0f);
    r[2] = fmaxf(fmaf(a[2], dv, b0.z), 0.0f);
    r[3] = fmaxf(fmaf(a[3], dv, b0.w), 0.0f);
    r[4] = fmaxf(fmaf(a[4], dv, b1.x), 0.0f);
    r[5] = fmaxf(fmaf(a[5], dv, b1.y), 0.0f);
    r[6] = fmaxf(fmaf(a[6], dv, b1.z), 0.0f);
    r[7] = fmaxf(fmaf(a[7], dv, b1.w), 0.0f);
    float s0 = 0.0f, s1 = 0.0f;
    #pragma unroll
    for (int i = 0; i < 8; ++i) {
        float2 w = sW[j + i];
        s0 = fmaf(r[i], w.x, s0);
        s1 = fmaf(r[i], w.y, s1);
    }
    #pragma unroll
    for (int off = 16; off >= 1; off >>= 1) {
        s0 += __shfl_down(s0, off, 32);
        s1 += __shfl_down(s1, off, 32);
    }
    if (l == 0)
        *(float2*)(g4 + (size_t)node * 2) = make_float2(s0 * dv, s1 * dv);
}

// ---- fused tail: per-graph, aggregate g4 over edges + mean-pool + c4 -> out ----
__global__ __launch_bounds__(256) void k_tail(const int* __restrict__ rowptr,
                                              const int* __restrict__ col,
                                              const float* __restrict__ g4,
                                              const float* __restrict__ dinv,
                                              const int* __restrict__ gptr,
                                              const float* __restrict__ c4,
                                              float* __restrict__ out) {
    int gph = blockIdx.x * 4 + (threadIdx.x >> 6);
    if (gph >= NG) return;
    int lane = threadIdx.x & 63;
    int b = gptr[gph], e = gptr[gph + 1];
    float s0 = 0.0f, s1 = 0.0f;
    for (int n = b + lane; n < e; n += 64) {
        float2 a = *(const float2*)(g4 + (size_t)n * 2);
        int ee = rowptr[n], eend = rowptr[n + 1];
        for (; ee < eend; ++ee) {
            float2 w = *(const float2*)(g4 + (size_t)col[ee] * 2);
            a.x += w.x; a.y += w.y;
        }
        float dv = dinv[n];
        s0 = fmaf(a.x, dv, s0);
        s1 = fmaf(a.y, dv, s1);
    }
    #pragma unroll
    for (int off = 32; off >= 1; off >>= 1) {
        s0 += __shfl_down(s0, off);
        s1 += __shfl_down(s1, off);
    }
    if (lane == 0) {
        float inv = 1.0f / fmaxf((float)(e - b), 1.0f);
        out[gph * 2 + 0] = s0 * inv + c4[0];
        out[gph * 2 + 1] = s1 * inv + c4[1];
    }
}

extern "C" void kernel_launch(void* const* d_in, const int* in_sizes, int n_in,
                              void* d_out, int out_size, void* d_ws, size_t ws_size,
                              hipStream_t stream) {
    const float* x   = (const float*)d_in[0];
    const int* ei    = (const int*)d_in[1];
    const int* src   = ei;
    const int* dst   = ei + N_EDGES;
    const int* batch = (const int*)d_in[2];
    const float* W1 = (const float*)d_in[3];  const float* b1 = (const float*)d_in[4];
    const float* W2 = (const float*)d_in[5];  const float* b2 = (const float*)d_in[6];
    const float* W3 = (const float*)d_in[7];  const float* b3 = (const float*)d_in[8];
    const float* W4 = (const float*)d_in[9];  const float* b4 = (const float*)d_in[10];
    const float* Wl = (const float*)d_in[11]; const float* bl = (const float*)d_in[12];
    float* out = (float*)d_out;

    // ---- workspace layout ----
    char* p = (char*)d_ws;
    auto take = [&](size_t bytes) { char* r = p; p += (bytes + 255) & ~(size_t)255; return r; };
    size_t zbytes = (size_t)(N_NODES + N_NODES) * 4;   // deg | fill
    int*   deg  = (int*)take(zbytes);
    int*   fill = deg + N_NODES;
    float* dinv = (float*)take((size_t)N_NODES * sizeof(float));
    int* rowptr = (int*)take((size_t)(N_NODES + 1) * sizeof(int));
    int* col    = (int*)take((size_t)N_EDGES * sizeof(int));
    int* bsum   = (int*)take((size_t)SCAN_B * sizeof(int));
    int* boff   = (int*)take((size_t)SCAN_B * sizeof(int));
    int* gptr   = (int*)take((size_t)(NG + 1) * sizeof(int));
    float* W4l  = (float*)take((size_t)HID * 2 * sizeof(float));
    float* c4   = (float*)take(2 * sizeof(float));
    float* g4   = (float*)take((size_t)N_NODES * 2 * sizeof(float));
    u16* Wt1 = (u16*)take((size_t)HID * KPA * 2);
    u16* Wt2 = (u16*)take((size_t)HID * HID * 2);
    u16* Wt3 = (u16*)take((size_t)HID * HID * 2);
    u16* Xs  = (u16*)take((size_t)N_NODES * KPX * 2);
    u16* Xa  = (u16*)take((size_t)M_PAD * KPA * 2);    // padded rows for GEMM staging
    u16* Gbuf = (u16*)take((size_t)N_NODES * HID * 2);
    u16* Xbuf = (u16*)take((size_t)M_PAD * HID * 2);   // padded rows for GEMM staging

    hipMemsetAsync(deg, 0, zbytes, stream);

    // CSR build + norms + prep
    k_deg<<<(N_EDGES + 255) / 256, 256, 0, stream>>>(dst, deg);
    k_scan_local<<<SCAN_B, 256, 0, stream>>>(deg, rowptr, bsum, dinv);
    k_scan_bsum<<<1, 512, 0, stream>>>(bsum, boff);
    k_scan_add<<<SCAN_B, 256, 0, stream>>>(rowptr, boff);
    k_fill_pad<<<FILL_B + (N_NODES + 3) / 4, 256, 0, stream>>>(src, dst, rowptr, fill, col,
                                                               x, dinv, Xs);
    k_prep<<<KPA + 2 * HID + 1 + (NG + 256) / 256, 256, 0, stream>>>(
        W1, W2, W3, W4, Wl, b4, bl, batch, Wt1, Wt2, Wt3, W4l, c4, gptr);

    const int nb8 = (N_NODES + 7) / 8;
    const dim3 gemm_grid(HID / 128, M_PAD / 128);   // col fast, row slow

    // layer 1: aggregate-first in input space, bias+relu fused in GEMM
    k_agg96<<<nb8, 256, 0, stream>>>(rowptr, col, Xs, dinv, Xa);
    k_gemm<1><<<gemm_grid, 256, 0, stream>>>(Xa, KPA, Wt1, dinv, b1, Xbuf);
    // layer 2
    k_gemm<0><<<gemm_grid, 256, 0, stream>>>(Xbuf, HID, Wt2, dinv, b2, Gbuf);
    k_agg256<<<nb8, 256, 0, stream>>>(rowptr, col, Gbuf, dinv, b2, Xbuf);
    // layer 3 GEMM -> g3; then fused agg+relu+head projection -> g4
    k_gemm<0><<<gemm_grid, 256, 0, stream>>>(Xbuf, HID, Wt3, dinv, b3, Gbuf);
    k_agg_head<<<nb8, 256, 0, stream>>>(rowptr, col, Gbuf, dinv, b3, W4l, g4);
    // fused tail: 2-dim aggregate + mean-pool + head constant
    k_tail<<<(NG + 3) / 4, 256, 0, stream>>>(rowptr, col, g4, dinv, gptr, c4, out);
}

// Round 11
// 364.532 us; speedup vs baseline: 1.2464x; 1.0243x over previous
//
#include <hip/hip_runtime.h>
#include <hip/hip_bf16.h>

#define N_NODES 100000
#define M_PAD   100096   // 782 * 128, so 128-row GEMM tiles never read OOB
#define M_TILES 782
#define N_EDGES 400000
#define IN_DIM  69
#define KPX     96       // Xs pitch (gather space for layer-1 aggregate)
#define KPA     128      // Xa pitch (layer-1 GEMM K, padded to BK multiple)
#define HID     256
#define NG      4096
#define SCAN_B  391      // ceil(N_NODES / 256)
#define FILL_B  1563     // ceil(N_EDGES / 256)
// GEMM grid: 98 groups of 16 bids; bid -> (row = (bid>>4)*8 + (bid&7), col = (bid>>3)&1)
// pairs (row,col0)/(row,col1) are 8 bids apart AND congruent mod 8 -> same XCD L2.
#define GEMM_BLOCKS (98 * 16)

typedef __attribute__((ext_vector_type(8))) short bf16x8;
typedef __attribute__((ext_vector_type(4))) float f32x4;
typedef unsigned short u16;
typedef unsigned int   u32;

__device__ __forceinline__ float b2f(u16 v) {
    u32 x = ((u32)v) << 16;
    return __builtin_bit_cast(float, x);
}
__device__ __forceinline__ u16 f2b(float f) {
    u32 x = __builtin_bit_cast(u32, f);
    u32 r = (x + 0x7FFF + ((x >> 16) & 1)) >> 16;   // RNE
    return (u16)r;
}
__device__ __forceinline__ float lo16(u32 v) { return b2f((u16)(v & 0xffff)); }
__device__ __forceinline__ float hi16(u32 v) { return b2f((u16)(v >> 16)); }

__device__ __forceinline__ void acc8(float* a, uint4 w, float m) {
    a[0] = fmaf(m, lo16(w.x), a[0]); a[1] = fmaf(m, hi16(w.x), a[1]);
    a[2] = fmaf(m, lo16(w.y), a[2]); a[3] = fmaf(m, hi16(w.y), a[3]);
    a[4] = fmaf(m, lo16(w.z), a[4]); a[5] = fmaf(m, hi16(w.z), a[5]);
    a[6] = fmaf(m, lo16(w.w), a[6]); a[7] = fmaf(m, hi16(w.w), a[7]);
}
__device__ __forceinline__ void acc4(float* a, uint2 w, float m) {
    a[0] = fmaf(m, lo16(w.x), a[0]); a[1] = fmaf(m, hi16(w.x), a[1]);
    a[2] = fmaf(m, lo16(w.y), a[2]); a[3] = fmaf(m, hi16(w.y), a[3]);
}

// async global->LDS, 16B per lane; LDS dest = wave-uniform base + lane*16
__device__ __forceinline__ void gl_lds16(const u16* g, u16* l) {
    __builtin_amdgcn_global_load_lds(
        (const __attribute__((address_space(1))) void*)g,
        (__attribute__((address_space(3))) void*)l, 16, 0, 0);
}

// ---- in-degree count (int) ----
__global__ void k_deg(const int* __restrict__ dst, int* __restrict__ deg) {
    int e = blockIdx.x * blockDim.x + threadIdx.x;
    if (e < N_EDGES) atomicAdd(&deg[dst[e]], 1);
}

// ---- local scan + dinv fused ----
__global__ void k_scan_local(const int* __restrict__ deg, int* __restrict__ rowptr,
                             int* __restrict__ bsum, float* __restrict__ dinv) {
    __shared__ int s[256];
    int tid = threadIdx.x;
    int i = blockIdx.x * 256 + tid;
    int v = (i < N_NODES) ? deg[i] : 0;
    if (i < N_NODES) dinv[i] = rsqrtf((float)v + 1.0f);
    s[tid] = v;
    __syncthreads();
    #pragma unroll
    for (int off = 1; off < 256; off <<= 1) {
        int t = 0;
        if (tid >= off) t = s[tid - off];
        __syncthreads();
        if (tid >= off) s[tid] += t;
        __syncthreads();
    }
    if (i < N_NODES) rowptr[i] = s[tid] - v;          // exclusive
    if (tid == 255) bsum[blockIdx.x] = s[255];        // block total
}

__global__ void k_scan_bsum(int* __restrict__ bsum, int* __restrict__ boff) {
    __shared__ int s[512];
    int tid = threadIdx.x;
    int v = (tid < SCAN_B) ? bsum[tid] : 0;
    s[tid] = v;
    __syncthreads();
    #pragma unroll
    for (int off = 1; off < 512; off <<= 1) {
        int t = 0;
        if (tid >= off) t = s[tid - off];
        __syncthreads();
        if (tid >= off) s[tid] += t;
        __syncthreads();
    }
    if (tid < SCAN_B) boff[tid] = s[tid] - v;         // exclusive
}

__global__ void k_scan_add(int* __restrict__ rowptr, const int* __restrict__ boff) {
    int i = blockIdx.x * 256 + threadIdx.x;
    if (i < N_NODES) rowptr[i] += boff[blockIdx.x];
    if (i == 0) rowptr[N_NODES] = N_EDGES;
}

// ---- CSR fill + Xs = dinv.*x pad/scale, merged ----
__global__ __launch_bounds__(256) void k_fill_pad(const int* __restrict__ src,
                       const int* __restrict__ dst,
                       const int* __restrict__ rowptr, int* __restrict__ fill,
                       int* __restrict__ col,
                       const float* __restrict__ x, const float* __restrict__ dinv,
                       u16* __restrict__ xs) {
    if (blockIdx.x < FILL_B) {
        int e = blockIdx.x * 256 + threadIdx.x;
        if (e < N_EDGES) {
            int d = dst[e];
            int pos = rowptr[d] + atomicAdd(&fill[d], 1);
            col[pos] = src[e];
        }
    } else {
        int node = (blockIdx.x - FILL_B) * 4 + (threadIdx.x >> 6);
        if (node >= N_NODES) return;
        int lane = threadIdx.x & 63;
        if (lane >= 48) return;
        int d0 = lane * 2, d1 = lane * 2 + 1;
        float dv = dinv[node];
        const float* xr = x + (size_t)node * IN_DIM;
        float v0 = (d0 < IN_DIM) ? xr[d0] * dv : 0.0f;
        float v1 = (d1 < IN_DIM) ? xr[d1] * dv : 0.0f;
        u32 o = (u32)f2b(v0) | ((u32)f2b(v1) << 16);
        *(u32*)(xs + (size_t)node * KPX + d0) = o;
    }
}

// ---- merged prep: W1/W2/W3 transpose->bf16, W4@Wl fold, gptr search ----
__global__ void k_prep(const float* __restrict__ W1, const float* __restrict__ W2,
                       const float* __restrict__ W3, const float* __restrict__ W4,
                       const float* __restrict__ Wl, const float* __restrict__ b4,
                       const float* __restrict__ bl, const int* __restrict__ batch,
                       u16* __restrict__ Wt1, u16* __restrict__ Wt2, u16* __restrict__ Wt3,
                       float* __restrict__ W4l, float* __restrict__ c4, int* __restrict__ gptr) {
    int b = blockIdx.x;
    int t = threadIdx.x;
    if (b < KPA) {                       // Wt1 [256 x 128], zero-padded K
        Wt1[(size_t)t * KPA + b] = (b < IN_DIM) ? f2b(W1[(size_t)b * HID + t]) : (u16)0;
    } else if (b < KPA + HID) {          // Wt2 [256 x 256]
        int k = b - KPA;
        Wt2[(size_t)t * HID + k] = f2b(W2[(size_t)k * HID + t]);
    } else if (b < KPA + 2 * HID) {      // Wt3
        int k = b - KPA - HID;
        Wt3[(size_t)t * HID + k] = f2b(W3[(size_t)k * HID + t]);
    } else if (b == KPA + 2 * HID) {     // W4l = W4 @ Wl ; c4 = b4 @ Wl + bl
        float s0 = 0.0f, s1 = 0.0f;
        const float* wr = W4 + (size_t)t * HID;
        for (int j = 0; j < HID; ++j) {
            float w = wr[j];
            s0 += w * Wl[j * 2 + 0];
            s1 += w * Wl[j * 2 + 1];
        }
        W4l[t * 2 + 0] = s0;
        W4l[t * 2 + 1] = s1;
        if (t < 2) {
            float s = bl[t];
            for (int j = 0; j < HID; ++j) s += b4[j] * Wl[j * 2 + t];
            c4[t] = s;
        }
    } else {                             // gptr: lower_bound(batch, g)
        int g = (b - (KPA + 2 * HID + 1)) * 256 + t;
        if (g > NG) return;
        if (g == NG) { gptr[NG] = N_NODES; return; }
        int lo = 0, hi = N_NODES;
        while (lo < hi) {
            int mid = (lo + hi) >> 1;
            if (batch[mid] < g) lo = mid + 1; else hi = mid;
        }
        gptr[g] = lo;
    }
}

// ---- 96-dim aggregate -> Xa [M_PAD x 128]; 32 lanes/node, predicated unroll-8 ----
__global__ __launch_bounds__(256) void k_agg96(const int* __restrict__ rowptr,
                                               const int* __restrict__ col,
                                               const u16* __restrict__ xs,
                                               const float* __restrict__ dinv,
                                               u16* __restrict__ xa) {
    int node = blockIdx.x * 8 + (threadIdx.x >> 5);
    if (node >= N_NODES) return;
    int l = threadIdx.x & 31;
    int j = l * 4;
    if (l >= 24) {                       // K-pad region (dims 96..127) -> zero
        *(uint2*)(xa + (size_t)node * KPA + j) = make_uint2(0, 0);
        return;
    }
    const u16* xj = xs + j;
    float a[4];
    {
        uint2 v = *(const uint2*)(xj + (size_t)node * KPX);
        a[0] = lo16(v.x); a[1] = hi16(v.x); a[2] = lo16(v.y); a[3] = hi16(v.y);
    }
    int e = rowptr[node], end = rowptr[node + 1];
    for (; e < end; e += 8) {
        int idx[8]; float mm[8];
        #pragma unroll
        for (int u = 0; u < 8; ++u) {
            int ee = e + u;
            idx[u] = (ee < end) ? ee : e;
            mm[u]  = (ee < end) ? 1.0f : 0.0f;
        }
        mm[0] = 1.0f;
        uint2 w[8];
        #pragma unroll
        for (int u = 0; u < 8; ++u) w[u] = *(const uint2*)(xj + (size_t)col[idx[u]] * KPX);
        #pragma unroll
        for (int u = 0; u < 8; ++u) acc4(a, w[u], mm[u]);
    }
    float dv = dinv[node];
    uint2 o;
    o.x = (u32)f2b(a[0] * dv) | ((u32)f2b(a[1] * dv) << 16);
    o.y = (u32)f2b(a[2] * dv) | ((u32)f2b(a[3] * dv) << 16);
    *(uint2*)(xa + (size_t)node * KPA + j) = o;
}

// ---- 128x128-tile MFMA GEMM, global_load_lds staging, XOR-swizzled LDS ----
// Linear grid GEMM_BLOCKS; bid -> (row,col) such that the two column-tiles of a
// row share XCD (bid mod 8 equal) and are 8 dispatch slots apart -> A-tile L2 reuse.
// MODE 0: Out = dinv[m]*(A@Wt^T).  MODE 1: Out = relu(A@Wt^T + bias).
template<int MODE>
__global__ __launch_bounds__(256) void k_gemm(const u16* __restrict__ A, int KP,
                                              const u16* __restrict__ Wt,
                                              const float* __restrict__ dinv,
                                              const float* __restrict__ bias,
                                              u16* __restrict__ Out) {
    __shared__ __align__(16) u16 As[128 * 64];   // [row][chunk ^ (row&7)]
    __shared__ __align__(16) u16 Bs[128 * 64];

    const int bid  = blockIdx.x;
    const int row  = (bid >> 4) * 8 + (bid & 7);
    if (row >= M_TILES) return;
    const int m0   = row * 128;
    const int n0   = ((bid >> 3) & 1) * 128;

    const int tid  = threadIdx.x;
    const int wave = tid >> 6;
    const int lane = tid & 63;
    const int quad = lane >> 4;
    const int lm   = lane & 15;
    const int wr   = wave >> 1;
    const int wc   = wave & 1;

    f32x4 acc[4][4] = {};

    const int sr = lane >> 3;
    const int sc = lane & 7;
    const int gc = sc ^ (sr & 7);

    for (int kt = 0; kt < KP; kt += 64) {
        __syncthreads();
        #pragma unroll
        for (int i = 0; i < 4; ++i) {
            int s = wave * 4 + i;
            int r = s * 8 + sr;
            const u16* ga = A  + (size_t)(m0 + r) * KP + kt + gc * 8;
            const u16* gb = Wt + (size_t)(n0 + r) * KP + kt + gc * 8;
            gl_lds16(ga, As + s * 512);
            gl_lds16(gb, Bs + s * 512);
        }
        __syncthreads();

        #pragma unroll
        for (int st = 0; st < 2; ++st) {
            bf16x8 af[4], bfr[4];
            const int slot = ((st * 4 + quad) ^ (lm & 7)) * 8;
            #pragma unroll
            for (int rt = 0; rt < 4; ++rt)
                af[rt] = *(const bf16x8*)(As + (wr * 64 + rt * 16 + lm) * 64 + slot);
            #pragma unroll
            for (int ct = 0; ct < 4; ++ct)
                bfr[ct] = *(const bf16x8*)(Bs + (wc * 64 + ct * 16 + lm) * 64 + slot);
            #pragma unroll
            for (int rt = 0; rt < 4; ++rt)
                #pragma unroll
                for (int ct = 0; ct < 4; ++ct)
                    acc[rt][ct] = __builtin_amdgcn_mfma_f32_16x16x32_bf16(af[rt], bfr[ct], acc[rt][ct], 0, 0, 0);
        }
    }

    #pragma unroll
    for (int rt = 0; rt < 4; ++rt) {
        #pragma unroll
        for (int reg = 0; reg < 4; ++reg) {
            int m = m0 + wr * 64 + rt * 16 + quad * 4 + reg;
            if (m >= N_NODES) continue;
            float dv = (MODE == 0) ? dinv[m] : 0.0f;
            #pragma unroll
            for (int ct = 0; ct < 4; ++ct) {
                int n = n0 + wc * 64 + ct * 16 + lm;
                float v = acc[rt][ct][reg];
                if (MODE == 0) v *= dv;
                else           v = fmaxf(v + bias[n], 0.0f);
                Out[(size_t)m * HID + n] = f2b(v);
            }
        }
    }
}

// ---- 256-dim aggregate + bias + relu; 32 lanes/node, 16B loads, predicated unroll-8 ----
__global__ __launch_bounds__(256) void k_agg256(const int* __restrict__ rowptr,
                                                const int* __restrict__ col,
                                                const u16* __restrict__ g,
                                                const float* __restrict__ dinv,
                                                const float* __restrict__ bias,
                                                u16* __restrict__ Xout) {
    int node = blockIdx.x * 8 + (threadIdx.x >> 5);
    if (node >= N_NODES) return;
    int l = threadIdx.x & 31;
    int j = l * 8;
    const u16* gj = g + j;

    float a[8];
    {
        uint4 v = *(const uint4*)(gj + (size_t)node * HID);
        a[0] = lo16(v.x); a[1] = hi16(v.x); a[2] = lo16(v.y); a[3] = hi16(v.y);
        a[4] = lo16(v.z); a[5] = hi16(v.z); a[6] = lo16(v.w); a[7] = hi16(v.w);
    }
    int e = rowptr[node], end = rowptr[node + 1];
    for (; e < end; e += 8) {
        int idx[8]; float mm[8];
        #pragma unroll
        for (int u = 0; u < 8; ++u) {
            int ee = e + u;
            idx[u] = (ee < end) ? ee : e;
            mm[u]  = (ee < end) ? 1.0f : 0.0f;
        }
        mm[0] = 1.0f;
        uint4 w[8];
        #pragma unroll
        for (int u = 0; u < 8; ++u) w[u] = *(const uint4*)(gj + (size_t)col[idx[u]] * HID);
        #pragma unroll
        for (int u = 0; u < 8; ++u) acc8(a, w[u], mm[u]);
    }
    float dv = dinv[node];
    float4 b0 = *(const float4*)(bias + j);
    float4 b1 = *(const float4*)(bias + j + 4);
    float r0 = fmaxf(fmaf(a[0], dv, b0.x), 0.0f);
    float r1 = fmaxf(fmaf(a[1], dv, b0.y), 0.0f);
    float r2 = fmaxf(fmaf(a[2], dv, b0.z), 0.0f);
    float r3 = fmaxf(fmaf(a[3], dv, b0.w), 0.0f);
    float r4 = fmaxf(fmaf(a[4], dv, b1.x), 0.0f);
    float r5 = fmaxf(fmaf(a[5], dv, b1.y), 0.0f);
    float r6 = fmaxf(fmaf(a[6], dv, b1.z), 0.0f);
    float r7 = fmaxf(fmaf(a[7], dv, b1.w), 0.0f);
    uint4 o;
    o.x = (u32)f2b(r0) | ((u32)f2b(r1) << 16);
    o.y = (u32)f2b(r2) | ((u32)f2b(r3) << 16);
    o.z = (u32)f2b(r4) | ((u32)f2b(r5) << 16);
    o.w = (u32)f2b(r6) | ((u32)f2b(r7) << 16);
    *(uint4*)(Xout + (size_t)node * HID + j) = o;
}

// ---- fused layer-3 agg + relu + W4l projection -> g4 [N x 2] f32 ----
__global__ __launch_bounds__(256) void k_agg_head(const int* __restrict__ rowptr,
                                                  const int* __restrict__ col,
                                                  const u16* __restrict__ g,
                                                  const float* __restrict__ dinv,
                                                  const float* __restrict__ bias,
                                                  const float* __restrict__ W4l,
                                                  float* __restrict__ g4) {
    __shared__ float2 sW[HID];
    sW[threadIdx.x] = *(const float2*)(W4l + threadIdx.x * 2);
    __syncthreads();

    int node = blockIdx.x * 8 + (threadIdx.x >> 5);
    if (node >= N_NODES) return;
    int l = threadIdx.x & 31;
    int j = l * 8;
    const u16* gj = g + j;

    float a[8];
    {
        uint4 v = *(const uint4*)(gj + (size_t)node * HID);
        a[0] = lo16(v.x); a[1] = hi16(v.x); a[2] = lo16(v.y); a[3] = hi16(v.y);
        a[4] = lo16(v.z); a[5] = hi16(v.z); a[6] = lo16(v.w); a[7] = hi16(v.w);
    }
    int e = rowptr[node], end = rowptr[node + 1];
    for (; e < end; e += 8) {
        int idx[8]; float mm[8];
        #pragma unroll
        for (int u = 0; u < 8; ++u) {
            int ee = e + u;
            idx[u] = (ee < end) ? ee : e;
            mm[u]  = (ee < end) ? 1.0f : 0.0f;
        }
        mm[0] = 1.0f;
        uint4 w[8];
        #pragma unroll
        for (int u = 0; u < 8; ++u) w[u] = *(const uint4*)(gj + (size_t)col[idx[u]] * HID);
        #pragma unroll
        for (int u = 0; u < 8; ++u) acc8(a, w[u], mm[u]);
    }
    float dv = dinv[node];
    float4 b0 = *(const float4*)(bias + j);
    float4 b1 = *(const float4*)(bias + j + 4);
    float r[8];
    r[0] = fmaxf(fmaf(a[0], dv, b0.x), 0.0f);
    r[1] = fmaxf(fmaf(a[1], dv, b0.y), 0.0f);
    r[2] = fmaxf(fmaf(a[2], dv, b0.z), 0.0f);
    r[3] = fmaxf(fmaf(a[3], dv, b0.w), 0.0f);
    r[4] = fmaxf(fmaf(a[4], dv, b1.x), 0.0f);
    r[5] = fmaxf(fmaf(a[5], dv, b1.y), 0.0f);
    r[6] = fmaxf(fmaf(a[6], dv, b1.z), 0.0f);
    r[7] = fmaxf(fmaf(a[7], dv, b1.w), 0.0f);
    float s0 = 0.0f, s1 = 0.0f;
    #pragma unroll
    for (int i = 0; i < 8; ++i) {
        float2 w = sW[j + i];
        s0 = fmaf(r[i], w.x, s0);
        s1 = fmaf(r[i], w.y, s1);
    }
    #pragma unroll
    for (int off = 16; off >= 1; off >>= 1) {
        s0 += __shfl_down(s0, off, 32);
        s1 += __shfl_down(s1, off, 32);
    }
    if (l == 0)
        *(float2*)(g4 + (size_t)node * 2) = make_float2(s0 * dv, s1 * dv);
}

// ---- fused tail: per-graph, aggregate g4 over edges + mean-pool + c4 -> out ----
__global__ __launch_bounds__(256) void k_tail(const int* __restrict__ rowptr,
                                              const int* __restrict__ col,
                                              const float* __restrict__ g4,
                                              const float* __restrict__ dinv,
                                              const int* __restrict__ gptr,
                                              const float* __restrict__ c4,
                                              float* __restrict__ out) {
    int gph = blockIdx.x * 4 + (threadIdx.x >> 6);
    if (gph >= NG) return;
    int lane = threadIdx.x & 63;
    int b = gptr[gph], e = gptr[gph + 1];
    float s0 = 0.0f, s1 = 0.0f;
    for (int n = b + lane; n < e; n += 64) {
        float2 a = *(const float2*)(g4 + (size_t)n * 2);
        int ee = rowptr[n], eend = rowptr[n + 1];
        for (; ee < eend; ++ee) {
            float2 w = *(const float2*)(g4 + (size_t)col[ee] * 2);
            a.x += w.x; a.y += w.y;
        }
        float dv = dinv[n];
        s0 = fmaf(a.x, dv, s0);
        s1 = fmaf(a.y, dv, s1);
    }
    #pragma unroll
    for (int off = 32; off >= 1; off >>= 1) {
        s0 += __shfl_down(s0, off);
        s1 += __shfl_down(s1, off);
    }
    if (lane == 0) {
        float inv = 1.0f / fmaxf((float)(e - b), 1.0f);
        out[gph * 2 + 0] = s0 * inv + c4[0];
        out[gph * 2 + 1] = s1 * inv + c4[1];
    }
}

extern "C" void kernel_launch(void* const* d_in, const int* in_sizes, int n_in,
                              void* d_out, int out_size, void* d_ws, size_t ws_size,
                              hipStream_t stream) {
    const float* x   = (const float*)d_in[0];
    const int* ei    = (const int*)d_in[1];
    const int* src   = ei;
    const int* dst   = ei + N_EDGES;
    const int* batch = (const int*)d_in[2];
    const float* W1 = (const float*)d_in[3];  const float* b1 = (const float*)d_in[4];
    const float* W2 = (const float*)d_in[5];  const float* b2 = (const float*)d_in[6];
    const float* W3 = (const float*)d_in[7];  const float* b3 = (const float*)d_in[8];
    const float* W4 = (const float*)d_in[9];  const float* b4 = (const float*)d_in[10];
    const float* Wl = (const float*)d_in[11]; const float* bl = (const float*)d_in[12];
    float* out = (float*)d_out;

    // ---- workspace layout ----
    char* p = (char*)d_ws;
    auto take = [&](size_t bytes) { char* r = p; p += (bytes + 255) & ~(size_t)255; return r; };
    size_t zbytes = (size_t)(N_NODES + N_NODES) * 4;   // deg | fill
    int*   deg  = (int*)take(zbytes);
    int*   fill = deg + N_NODES;
    float* dinv = (float*)take((size_t)N_NODES * sizeof(float));
    int* rowptr = (int*)take((size_t)(N_NODES + 1) * sizeof(int));
    int* col    = (int*)take((size_t)N_EDGES * sizeof(int));
    int* bsum   = (int*)take((size_t)SCAN_B * sizeof(int));
    int* boff   = (int*)take((size_t)SCAN_B * sizeof(int));
    int* gptr   = (int*)take((size_t)(NG + 1) * sizeof(int));
    float* W4l  = (float*)take((size_t)HID * 2 * sizeof(float));
    float* c4   = (float*)take(2 * sizeof(float));
    float* g4   = (float*)take((size_t)N_NODES * 2 * sizeof(float));
    u16* Wt1 = (u16*)take((size_t)HID * KPA * 2);
    u16* Wt2 = (u16*)take((size_t)HID * HID * 2);
    u16* Wt3 = (u16*)take((size_t)HID * HID * 2);
    u16* Xs  = (u16*)take((size_t)N_NODES * KPX * 2);
    u16* Xa  = (u16*)take((size_t)M_PAD * KPA * 2);    // padded rows for GEMM staging
    u16* Gbuf = (u16*)take((size_t)N_NODES * HID * 2);
    u16* Xbuf = (u16*)take((size_t)M_PAD * HID * 2);   // padded rows for GEMM staging

    hipMemsetAsync(deg, 0, zbytes, stream);

    // CSR build + norms + prep
    k_deg<<<(N_EDGES + 255) / 256, 256, 0, stream>>>(dst, deg);
    k_scan_local<<<SCAN_B, 256, 0, stream>>>(deg, rowptr, bsum, dinv);
    k_scan_bsum<<<1, 512, 0, stream>>>(bsum, boff);
    k_scan_add<<<SCAN_B, 256, 0, stream>>>(rowptr, boff);
    k_fill_pad<<<FILL_B + (N_NODES + 3) / 4, 256, 0, stream>>>(src, dst, rowptr, fill, col,
                                                               x, dinv, Xs);
    k_prep<<<KPA + 2 * HID + 1 + (NG + 256) / 256, 256, 0, stream>>>(
        W1, W2, W3, W4, Wl, b4, bl, batch, Wt1, Wt2, Wt3, W4l, c4, gptr);

    const int nb8 = (N_NODES + 7) / 8;

    // layer 1: aggregate-first in input space, bias+relu fused in GEMM
    k_agg96<<<nb8, 256, 0, stream>>>(rowptr, col, Xs, dinv, Xa);
    k_gemm<1><<<GEMM_BLOCKS, 256, 0, stream>>>(Xa, KPA, Wt1, dinv, b1, Xbuf);
    // layer 2
    k_gemm<0><<<GEMM_BLOCKS, 256, 0, stream>>>(Xbuf, HID, Wt2, dinv, b2, Gbuf);
    k_agg256<<<nb8, 256, 0, stream>>>(rowptr, col, Gbuf, dinv, b2, Xbuf);
    // layer 3 GEMM -> g3; then fused agg+relu+head projection -> g4
    k_gemm<0><<<GEMM_BLOCKS, 256, 0, stream>>>(Xbuf, HID, Wt3, dinv, b3, Gbuf);
    k_agg_head<<<nb8, 256, 0, stream>>>(rowptr, col, Gbuf, dinv, b3, W4l, g4);
    // fused tail: 2-dim aggregate + mean-pool + head constant
    k_tail<<<(NG + 3) / 4, 256, 0, stream>>>(rowptr, col, g4, dinv, gptr, c4, out);
}